// Round 6
// baseline (2756.824 us; speedup 1.0000x reference)
//
#include <hip/hip_runtime.h>
#include <hip/hip_bf16.h>
#include <stdint.h>

#define B_  4
#define S_  2048
#define BS_ (B_ * S_)   // 8192 tokens
#define D_  1024
#define O_  1024
#define H_  8

#define BM 256
#define BN 128
#define BK 64
#define KT 16           // D_/BK

typedef unsigned short u16;
typedef __attribute__((ext_vector_type(8))) short     short8;
typedef __attribute__((ext_vector_type(8))) unsigned short ushort8v;
typedef __attribute__((ext_vector_type(4))) float     f32x4;

__device__ __forceinline__ u16 f2bf(float f) {
  unsigned u = __float_as_uint(f);
  unsigned r = (u + 0x7fffu + ((u >> 16) & 1u)) >> 16;
  return (u16)r;
}

#define GLOAD16(gp, lp)                                                        \
  __builtin_amdgcn_global_load_lds(                                            \
      (const __attribute__((address_space(1))) void*)(gp),                     \
      (__attribute__((address_space(3))) void*)(lp), 16, 0, 0)

// ---------------------------------------------------------------------------
// Kernel 1: gates (f32, one wave per token) + x -> bf16 conversion
// ---------------------------------------------------------------------------
__global__ __launch_bounds__(256) void gate_conv_kernel(
    const float* __restrict__ x, const float* __restrict__ gate_w,
    const float* __restrict__ gate_b, u16* __restrict__ x_bf,
    float* __restrict__ g_out) {
  const int wave  = threadIdx.x >> 6;
  const int lane  = threadIdx.x & 63;
  const int token = blockIdx.x * 4 + wave;
  const float* xr = x + (size_t)token * D_;
  const int d0 = lane * 16;

  float4 xv[4];
#pragma unroll
  for (int i = 0; i < 4; ++i) xv[i] = *(const float4*)(xr + d0 + i * 4);

  ushort8v lo, hi;
#pragma unroll
  for (int i = 0; i < 2; ++i) {
    lo[i * 4 + 0] = f2bf(xv[i].x); lo[i * 4 + 1] = f2bf(xv[i].y);
    lo[i * 4 + 2] = f2bf(xv[i].z); lo[i * 4 + 3] = f2bf(xv[i].w);
    hi[i * 4 + 0] = f2bf(xv[2 + i].x); hi[i * 4 + 1] = f2bf(xv[2 + i].y);
    hi[i * 4 + 2] = f2bf(xv[2 + i].z); hi[i * 4 + 3] = f2bf(xv[2 + i].w);
  }
  *(ushort8v*)(x_bf + (size_t)token * D_ + d0) = lo;
  *(ushort8v*)(x_bf + (size_t)token * D_ + d0 + 8) = hi;

  float s[H_];
#pragma unroll
  for (int h = 0; h < H_; ++h) {
    const float* gw = gate_w + h * D_ + d0;
    float a = 0.f;
#pragma unroll
    for (int i = 0; i < 4; ++i) {
      float4 w = *(const float4*)(gw + i * 4);
      a += xv[i].x * w.x + xv[i].y * w.y + xv[i].z * w.z + xv[i].w * w.w;
    }
    s[h] = a;
  }
#pragma unroll
  for (int h = 0; h < H_; ++h) {
#pragma unroll
    for (int off = 32; off > 0; off >>= 1) s[h] += __shfl_xor(s[h], off);
    s[h] += gate_b[h];
  }
  float m = s[0];
#pragma unroll
  for (int h = 1; h < H_; ++h) m = fmaxf(m, s[h]);
  float sum = 0.f;
#pragma unroll
  for (int h = 0; h < H_; ++h) { s[h] = expf(s[h] - m); sum += s[h]; }
  const float inv = 1.0f / sum;
#pragma unroll
  for (int h = 0; h < H_; ++h) s[h] *= inv;

  if (lane == 0) {
    float4 g0 = make_float4(s[0], s[1], s[2], s[3]);
    float4 g1 = make_float4(s[4], s[5], s[6], s[7]);
    *(float4*)(g_out + (size_t)token * H_)     = g0;
    *(float4*)(g_out + (size_t)token * H_ + 4) = g1;
  }
}

// ---------------------------------------------------------------------------
// Kernel 2: expert_w f32 -> bf16
// ---------------------------------------------------------------------------
__global__ __launch_bounds__(256) void convw_kernel(
    const float* __restrict__ w, u16* __restrict__ wb) {
  size_t i = ((size_t)blockIdx.x * 256 + threadIdx.x) * 8;
  float4 a = *(const float4*)(w + i);
  float4 b = *(const float4*)(w + i + 4);
  ushort8v v;
  v[0] = f2bf(a.x); v[1] = f2bf(a.y); v[2] = f2bf(a.z); v[3] = f2bf(a.w);
  v[4] = f2bf(b.x); v[5] = f2bf(b.y); v[6] = f2bf(b.z); v[7] = f2bf(b.w);
  *(ushort8v*)(wb + i) = v;
}

// ---------------------------------------------------------------------------
// Kernel 3: fused MoE GEMM, k-outer / h-inner, A-frags register-resident.
//   out[r,c] = sum_h g[r,h]*(X[r,:]·W[h,c,:] + eb[h,c])
// BM=256 x BN=128, BK=64, 8 waves (2Mx4N, per-wave 128x32), grid=256.
// REGISTER BUDGET: live set acc(64)+part(64)+af(64)+bf/addr ~= 225 regs.
// __launch_bounds__ arg2 pinned the cap at 128 in R4/R5 regardless of value
// (VGPR_Count 64/128/128 at args 4/2/1) -> af spill-reloaded every step
// (~4.3 GB scratch traffic, matches measured 3.3/5.2 GB FETCH/WRITE).
// Fix: amdgpu_waves_per_eu(2,2) -> budget 512/2 = 256 regs/lane; a
// 512-thread group needs 2 waves/EU anyway, and LDS (143 KB) already limits
// to 1 block/CU, so nothing is lost.
// A double-buffered (staged once per k-tile, issued at h==5 so the in-order
// vmcnt queue doesn't force early completion), B 4-slot ring prefetched 2
// steps ahead, counted vmcnt (never 0 mid-loop), 3-bit XOR LDS swizzle,
// Abel fold: acc += dg_h * part (part = prefix over h, C=0 restart at h==0).
// vmcnt ledger (per wave; A=4 issues, B=2 issues):
//   prologue A0,B0,B1 -> vmcnt(2) [A0,B0 done].
//   step (k,h): issue B(s+2) [if s<126]; issue A(k+1) at h==5 [if k<15].
//   end-of-step waits: h<5: 2 | h=5: k<15?6:2 | h=6: k<15?6:0 | h=7: k<15?2:0
// ---------------------------------------------------------------------------
__global__ __launch_bounds__(512)
__attribute__((amdgpu_waves_per_eu(2, 2))) void moe_gemm_kernel(
    const u16* __restrict__ Xb, const u16* __restrict__ Wb,
    const float* __restrict__ g, const float* __restrict__ eb,
    float* __restrict__ out) {
  __shared__ __align__(16) u16 As[2][BM * BK];   // 2 x 32 KB
  __shared__ __align__(16) u16 Bs[4][BN * BK];   // 4 x 16 KB
  __shared__ float gs[H_][BM];                   // dg (Abel deltas), 8 KB
  __shared__ float ebs[H_][BN];                  // prefix-summed eb, 4 KB

  const int tid  = threadIdx.x;
  const int wave = tid >> 6;
  const int lane = tid & 63;

  const int bx   = blockIdx.x;          // 256 blocks; bx&7 -> XCD (W affinity)
  const int row0 = (bx >> 3) * BM;
  const int col0 = (bx & 7) * BN;

  // ---- stage dg = adjacent differences of g (Abel summation) ----
  if (tid < BM) {
    const float* gr = g + (size_t)(row0 + tid) * H_;
    float gv[H_];
#pragma unroll
    for (int h = 0; h < H_; ++h) gv[h] = gr[h];
#pragma unroll
    for (int h = 0; h < H_ - 1; ++h) gs[h][tid] = gv[h] - gv[h + 1];
    gs[H_ - 1][tid] = gv[H_ - 1];
  }
  for (int i = tid; i < H_ * BN; i += 512) {
    int h = i >> 7, c = i & 127;
    ebs[h][c] = eb[h * O_ + col0 + c];
  }
  __syncthreads();
  // prefix-sum eb over h (bias = sum_h g_h*eb_h = sum_h dg_h*E_h)
  if (tid < BN) {
    float run = ebs[0][tid];
#pragma unroll
    for (int h = 1; h < H_; ++h) { run += ebs[h][tid]; ebs[h][tid] = run; }
  }
  __syncthreads();

  // ---- staging geometry: linear LDS dest, inverse-swizzled global src ----
  // swizzle involution: elem_col ^= (row&7)<<3
  const int s_row = wave * 8 + (lane >> 3);
  const int s_col = ((lane & 7) * 8) ^ (((lane >> 3) & 7) << 3);
  const u16* a_base = Xb + (size_t)(row0 + s_row) * D_ + s_col;
  const int b_row   = col0 + s_row;
  const int lds_off = (wave * 8) * BK;   // elems, wave-uniform

#define STAGE_A(kk_, buf_)                                                     \
  {                                                                            \
    const u16* ap = a_base + (kk_) * BK;                                       \
    GLOAD16(ap,                     &As[buf_][lds_off]);                       \
    GLOAD16(ap + (size_t)64  * D_,  &As[buf_][lds_off + 64 * BK]);             \
    GLOAD16(ap + (size_t)128 * D_,  &As[buf_][lds_off + 128 * BK]);            \
    GLOAD16(ap + (size_t)192 * D_,  &As[buf_][lds_off + 192 * BK]);            \
  }
#define STAGE_B(hh_, kk_, sl_)                                                 \
  {                                                                            \
    const u16* bp = Wb + ((size_t)(hh_)*O_ + b_row) * D_ + (kk_)*BK + s_col;   \
    GLOAD16(bp,                    &Bs[sl_][lds_off]);                         \
    GLOAD16(bp + (size_t)64 * D_,  &Bs[sl_][lds_off + 64 * BK]);               \
  }

  // ---- swizzled LDS read offsets (elements) ----
  const int wm = wave >> 2;  // 0..1 : 128 rows
  const int wn = wave & 3;   // 0..3 : 32 cols
  const int sw  = (lane & 7) << 3;
  const int aq  = lane >> 4;
  const int ce0 = (aq * 8) ^ sw;
  const int ce1 = (aq * 8 + 32) ^ sw;
  const int arow0 = (wm * 128 + (lane & 15)) * BK;
  const int brow0 = (wn * 32 + (lane & 15)) * BK;

  const f32x4 zero4 = {0.f, 0.f, 0.f, 0.f};
  f32x4 acc[8][2];
#pragma unroll
  for (int i = 0; i < 8; ++i) { acc[i][0] = zero4; acc[i][1] = zero4; }
  f32x4 part[8][2];
  short8 af[8][2];

  // ---- prologue: A0(4), B0(2), B1(2) -> wait A0,B0 ----
  STAGE_A(0, 0);
  STAGE_B(0, 0, 0);
  STAGE_B(1, 0, 1);
  asm volatile("s_waitcnt vmcnt(2)" ::: "memory");
  __builtin_amdgcn_s_barrier();

  for (int k = 0; k < KT; ++k) {
    const u16* Ab = &As[k & 1][0];
#pragma unroll
    for (int h = 0; h < H_; ++h) {
      const int s = k * 8 + h;
      if (h == 0) {
#pragma unroll
        for (int fm = 0; fm < 8; ++fm) {
          af[fm][0] = *(const short8*)&Ab[arow0 + fm * 16 * BK + ce0];
          af[fm][1] = *(const short8*)&Ab[arow0 + fm * 16 * BK + ce1];
        }
      }
      const u16* Bb = &Bs[s & 3][0];
      const short8 bf00 = *(const short8*)&Bb[brow0 + ce0];
      const short8 bf01 = *(const short8*)&Bb[brow0 + ce1];
      const short8 bf10 = *(const short8*)&Bb[brow0 + 16 * BK + ce0];
      const short8 bf11 = *(const short8*)&Bb[brow0 + 16 * BK + ce1];

      // prefetch issues (B first, then A at h==5 so A stays outstanding
      // until the h==7 wait -- in-order vmcnt queue)
      if (s < KT * 8 - 2) {
        const int hp = (h + 2) & 7;
        const int kp = k + (h >= 6);
        STAGE_B(hp, kp, (s + 2) & 3);
      }
      if (h == 5 && k < KT - 1) STAGE_A(k + 1, (k + 1) & 1);

      __builtin_amdgcn_s_barrier();
      __builtin_amdgcn_s_setprio(1);
#pragma unroll
      for (int fm = 0; fm < 8; ++fm) {
        if (h == 0) {
          part[fm][0] = __builtin_amdgcn_mfma_f32_16x16x32_bf16(
              af[fm][0], bf00, zero4, 0, 0, 0);
          part[fm][1] = __builtin_amdgcn_mfma_f32_16x16x32_bf16(
              af[fm][0], bf10, zero4, 0, 0, 0);
        } else {
          part[fm][0] = __builtin_amdgcn_mfma_f32_16x16x32_bf16(
              af[fm][0], bf00, part[fm][0], 0, 0, 0);
          part[fm][1] = __builtin_amdgcn_mfma_f32_16x16x32_bf16(
              af[fm][0], bf10, part[fm][1], 0, 0, 0);
        }
        part[fm][0] = __builtin_amdgcn_mfma_f32_16x16x32_bf16(
            af[fm][1], bf01, part[fm][0], 0, 0, 0);
        part[fm][1] = __builtin_amdgcn_mfma_f32_16x16x32_bf16(
            af[fm][1], bf11, part[fm][1], 0, 0, 0);
      }
      __builtin_amdgcn_s_setprio(0);

      // Abel fold: acc += dg_h * P_h (dg reads are 16-lane broadcast-class)
#pragma unroll
      for (int fm = 0; fm < 8; ++fm) {
        const f32x4 dg =
            *(const f32x4*)&gs[h][wm * 128 + fm * 16 + (lane >> 4) * 4];
#pragma unroll
        for (int j = 0; j < 4; ++j) {
          acc[fm][0][j] += dg[j] * part[fm][0][j];
          acc[fm][1][j] += dg[j] * part[fm][1][j];
        }
      }

      // counted vmcnt per ledger
      if (h < 5) {
        asm volatile("s_waitcnt vmcnt(2)" ::: "memory");
      } else if (h == 5) {
        if (k < KT - 1) asm volatile("s_waitcnt vmcnt(6)" ::: "memory");
        else            asm volatile("s_waitcnt vmcnt(2)" ::: "memory");
      } else if (h == 6) {
        if (k < KT - 1) asm volatile("s_waitcnt vmcnt(6)" ::: "memory");
        else            asm volatile("s_waitcnt vmcnt(0)" ::: "memory");
      } else {
        if (k < KT - 1) asm volatile("s_waitcnt vmcnt(2)" ::: "memory");
        else            asm volatile("s_waitcnt vmcnt(0)" ::: "memory");
      }
      __builtin_amdgcn_s_barrier();
    }
  }

  // ---- epilogue: C/D layout col = lane&15, row = (lane>>4)*4 + j ----
  const int crow_l = wm * 128 + (lane >> 4) * 4;
  const int ccol_l = wn * 32 + (lane & 15);
#pragma unroll
  for (int fm = 0; fm < 8; ++fm) {
#pragma unroll
    for (int fn = 0; fn < 2; ++fn) {
#pragma unroll
      for (int j = 0; j < 4; ++j) {
        float b = 0.f;
#pragma unroll
        for (int h = 0; h < H_; ++h)
          b += gs[h][crow_l + fm * 16 + j] * ebs[h][ccol_l + fn * 16];
        out[(size_t)(row0 + crow_l + fm * 16 + j) * O_ +
            (col0 + ccol_l + fn * 16)] = acc[fm][fn][j] + b;
      }
    }
  }
}

// ---------------------------------------------------------------------------
extern "C" void kernel_launch(void* const* d_in, const int* in_sizes, int n_in,
                              void* d_out, int out_size, void* d_ws,
                              size_t ws_size, hipStream_t stream) {
  const float* x   = (const float*)d_in[0];
  const float* gw  = (const float*)d_in[1];
  const float* gb  = (const float*)d_in[2];
  const float* ew  = (const float*)d_in[3];
  const float* ebp = (const float*)d_in[4];
  float* out = (float*)d_out;

  u16*   x_bf = (u16*)d_ws;                                            // 16 MB
  u16*   w_bf = (u16*)((char*)d_ws + (size_t)BS_ * D_ * 2);            // 16 MB
  float* gbuf = (float*)((char*)d_ws + (size_t)BS_ * D_ * 2 +
                         (size_t)H_ * O_ * D_ * 2);                    // 256 KB

  gate_conv_kernel<<<BS_ / 4, 256, 0, stream>>>(x, gw, gb, x_bf, gbuf);
  convw_kernel<<<(H_ * O_ * D_) / 2048, 256, 0, stream>>>(ew, w_bf);
  moe_gemm_kernel<<<(BS_ / BM) * (O_ / BN), 512, 0, stream>>>(x_bf, w_bf, gbuf,
                                                              ebp, out);
}

// Round 7
// 523.802 us; speedup vs baseline: 5.2631x; 5.2631x over previous
//
#include <hip/hip_runtime.h>
#include <hip/hip_bf16.h>
#include <stdint.h>

#define B_  4
#define S_  2048
#define BS_ (B_ * S_)   // 8192 tokens
#define D_  1024
#define O_  1024
#define H_  8

#define BM 128
#define BN 128
#define BK 64
#define KT 16           // D_/BK

typedef unsigned short u16;
typedef __attribute__((ext_vector_type(8))) short     short8;
typedef __attribute__((ext_vector_type(8))) unsigned short ushort8v;
typedef __attribute__((ext_vector_type(4))) float     f32x4;

__device__ __forceinline__ u16 f2bf(float f) {
  unsigned u = __float_as_uint(f);
  unsigned r = (u + 0x7fffu + ((u >> 16) & 1u)) >> 16;
  return (u16)r;
}

#define GLOAD16(gp, lp)                                                        \
  __builtin_amdgcn_global_load_lds(                                            \
      (const __attribute__((address_space(1))) void*)(gp),                     \
      (__attribute__((address_space(3))) void*)(lp), 16, 0, 0)

// ---------------------------------------------------------------------------
// Kernel 1: gates (f32, one wave per token) + x -> bf16 conversion
// ---------------------------------------------------------------------------
__global__ __launch_bounds__(256) void gate_conv_kernel(
    const float* __restrict__ x, const float* __restrict__ gate_w,
    const float* __restrict__ gate_b, u16* __restrict__ x_bf,
    float* __restrict__ g_out) {
  const int wave  = threadIdx.x >> 6;
  const int lane  = threadIdx.x & 63;
  const int token = blockIdx.x * 4 + wave;
  const float* xr = x + (size_t)token * D_;
  const int d0 = lane * 16;

  float4 xv[4];
#pragma unroll
  for (int i = 0; i < 4; ++i) xv[i] = *(const float4*)(xr + d0 + i * 4);

  ushort8v lo, hi;
#pragma unroll
  for (int i = 0; i < 2; ++i) {
    lo[i * 4 + 0] = f2bf(xv[i].x); lo[i * 4 + 1] = f2bf(xv[i].y);
    lo[i * 4 + 2] = f2bf(xv[i].z); lo[i * 4 + 3] = f2bf(xv[i].w);
    hi[i * 4 + 0] = f2bf(xv[2 + i].x); hi[i * 4 + 1] = f2bf(xv[2 + i].y);
    hi[i * 4 + 2] = f2bf(xv[2 + i].z); hi[i * 4 + 3] = f2bf(xv[2 + i].w);
  }
  *(ushort8v*)(x_bf + (size_t)token * D_ + d0) = lo;
  *(ushort8v*)(x_bf + (size_t)token * D_ + d0 + 8) = hi;

  float s[H_];
#pragma unroll
  for (int h = 0; h < H_; ++h) {
    const float* gw = gate_w + h * D_ + d0;
    float a = 0.f;
#pragma unroll
    for (int i = 0; i < 4; ++i) {
      float4 w = *(const float4*)(gw + i * 4);
      a += xv[i].x * w.x + xv[i].y * w.y + xv[i].z * w.z + xv[i].w * w.w;
    }
    s[h] = a;
  }
#pragma unroll
  for (int h = 0; h < H_; ++h) {
#pragma unroll
    for (int off = 32; off > 0; off >>= 1) s[h] += __shfl_xor(s[h], off);
    s[h] += gate_b[h];
  }
  float m = s[0];
#pragma unroll
  for (int h = 1; h < H_; ++h) m = fmaxf(m, s[h]);
  float sum = 0.f;
#pragma unroll
  for (int h = 0; h < H_; ++h) { s[h] = expf(s[h] - m); sum += s[h]; }
  const float inv = 1.0f / sum;
#pragma unroll
  for (int h = 0; h < H_; ++h) s[h] *= inv;

  if (lane == 0) {
    float4 g0 = make_float4(s[0], s[1], s[2], s[3]);
    float4 g1 = make_float4(s[4], s[5], s[6], s[7]);
    *(float4*)(g_out + (size_t)token * H_)     = g0;
    *(float4*)(g_out + (size_t)token * H_ + 4) = g1;
  }
}

// ---------------------------------------------------------------------------
// Kernel 2: expert_w f32 -> bf16
// ---------------------------------------------------------------------------
__global__ __launch_bounds__(256) void convw_kernel(
    const float* __restrict__ w, u16* __restrict__ wb) {
  size_t i = ((size_t)blockIdx.x * 256 + threadIdx.x) * 8;
  float4 a = *(const float4*)(w + i);
  float4 b = *(const float4*)(w + i + 4);
  ushort8v v;
  v[0] = f2bf(a.x); v[1] = f2bf(a.y); v[2] = f2bf(a.z); v[3] = f2bf(a.w);
  v[4] = f2bf(b.x); v[5] = f2bf(b.y); v[6] = f2bf(b.z); v[7] = f2bf(b.w);
  *(ushort8v*)(wb + i) = v;
}

// ---------------------------------------------------------------------------
// Kernel 3: fused MoE GEMM, k-outer / h-inner, sized to FIT 128 VGPRs.
//   out[r,c] = sum_h g[r,h]*(X[r,:]·W[h,c,:] + eb[h,c])
// BM=128 x BN=128, BK=64, 8 waves (2Mx4N, per-wave 64x32), grid=512.
// R4-R6 lesson: 512-thr kernels get a 128-VGPR cap on this toolchain no
// matter which occupancy attribute is used (VGPR_Count==128 across three
// settings; 5.2 GB scratch). Per-wave 128x32 needed ~225 regs -> spill.
// This version: acc[4][2](32) + part[4][2](32) + af[4][2](32) + bf(16)
// + dg(4) + addr(~15) ~= 120 regs -> no spill at cap 128.
// A double-buffered (2 issues/k-tile, issued at h==5), B 4-slot ring
// (2 issues/step) prefetched 2 steps ahead, counted vmcnt (never 0
// mid-loop), 3-bit XOR swizzle (0 conflicts measured R4-R6), Abel fold
// acc += dg_h*part with dg[h]=g[h]-g[h+1]; bias via prefix-summed eb.
// vmcnt ledger (A=2, B=2 per issue; invariant entering step s: B(s+1)=2):
//   prologue A0,B0,B1 -> vmcnt(2).
//   step (k,h): issue B(s+2) [if k<15||h<6]; issue A(k+1) at h==5 [k<15].
//   waits: h<5: 2 | h5: k<15?4:2 | h6: k<15?4:0 | h7: k<15?2:0.
// col0 = (bx&7)*BN: XCD-affine -> each XCD's 2MB W panel stays L2-resident;
// X (16 MB) serves from L3.
// ---------------------------------------------------------------------------
__global__ __launch_bounds__(512) void moe_gemm_kernel(
    const u16* __restrict__ Xb, const u16* __restrict__ Wb,
    const float* __restrict__ g, const float* __restrict__ eb,
    float* __restrict__ out) {
  __shared__ __align__(16) u16 As[2][BM * BK];   // 2 x 16 KB
  __shared__ __align__(16) u16 Bs[4][BN * BK];   // 4 x 16 KB
  __shared__ float gs[H_][BM];                   // dg (Abel deltas), 4 KB
  __shared__ float ebs[H_][BN];                  // prefix-summed eb, 4 KB

  const int tid  = threadIdx.x;
  const int wave = tid >> 6;
  const int lane = tid & 63;

  const int bx   = blockIdx.x;          // 512 blocks; bx&7 -> XCD (W affinity)
  const int row0 = (bx >> 3) * BM;      // 64 row tiles
  const int col0 = (bx & 7) * BN;       // 8 col tiles

  // ---- stage dg = adjacent differences of g (Abel summation) ----
  if (tid < BM) {
    const float* gr = g + (size_t)(row0 + tid) * H_;
    float gv[H_];
#pragma unroll
    for (int h = 0; h < H_; ++h) gv[h] = gr[h];
#pragma unroll
    for (int h = 0; h < H_ - 1; ++h) gs[h][tid] = gv[h] - gv[h + 1];
    gs[H_ - 1][tid] = gv[H_ - 1];
  }
  for (int i = tid; i < H_ * BN; i += 512) {
    int h = i >> 7, c = i & 127;
    ebs[h][c] = eb[h * O_ + col0 + c];
  }
  __syncthreads();
  // prefix-sum eb over h (bias = sum_h g_h*eb_h = sum_h dg_h*E_h)
  if (tid < BN) {
    float run = ebs[0][tid];
#pragma unroll
    for (int h = 1; h < H_; ++h) { run += ebs[h][tid]; ebs[h][tid] = run; }
  }
  __syncthreads();

  // ---- staging geometry: linear LDS dest, inverse-swizzled global src ----
  // swizzle involution: elem_col ^= (row&7)<<3
  const int s_row = wave * 8 + (lane >> 3);
  const int s_col = ((lane & 7) * 8) ^ (((lane >> 3) & 7) << 3);
  const u16* a_base = Xb + (size_t)(row0 + s_row) * D_ + s_col;
  const int b_row   = col0 + s_row;
  const int lds_off = (wave * 8) * BK;   // elems, wave-uniform

#define STAGE_A(kk_, buf_)                                                     \
  {                                                                            \
    const u16* ap = a_base + (kk_) * BK;                                       \
    GLOAD16(ap,                    &As[buf_][lds_off]);                        \
    GLOAD16(ap + (size_t)64 * D_,  &As[buf_][lds_off + 64 * BK]);              \
  }
#define STAGE_B(hh_, kk_, sl_)                                                 \
  {                                                                            \
    const u16* bp = Wb + ((size_t)(hh_)*O_ + b_row) * D_ + (kk_)*BK + s_col;   \
    GLOAD16(bp,                    &Bs[sl_][lds_off]);                         \
    GLOAD16(bp + (size_t)64 * D_,  &Bs[sl_][lds_off + 64 * BK]);               \
  }

  // ---- swizzled LDS read offsets (elements) ----
  const int wm = wave >> 2;  // 0..1 : 64 rows
  const int wn = wave & 3;   // 0..3 : 32 cols
  const int sw  = (lane & 7) << 3;
  const int aq  = lane >> 4;
  const int ce0 = (aq * 8) ^ sw;
  const int ce1 = (aq * 8 + 32) ^ sw;
  const int arow0 = (wm * 64 + (lane & 15)) * BK;
  const int brow0 = (wn * 32 + (lane & 15)) * BK;

  const f32x4 zero4 = {0.f, 0.f, 0.f, 0.f};
  f32x4 acc[4][2];
#pragma unroll
  for (int i = 0; i < 4; ++i) { acc[i][0] = zero4; acc[i][1] = zero4; }
  f32x4 part[4][2];
  short8 af[4][2];

  // ---- prologue: A0(2), B0(2), B1(2) -> wait A0,B0 ----
  STAGE_A(0, 0);
  STAGE_B(0, 0, 0);
  STAGE_B(1, 0, 1);
  asm volatile("s_waitcnt vmcnt(2)" ::: "memory");
  __builtin_amdgcn_s_barrier();

  for (int k = 0; k < KT; ++k) {
    const u16* Ab = &As[k & 1][0];
#pragma unroll
    for (int h = 0; h < H_; ++h) {
      if (h == 0) {
#pragma unroll
        for (int fm = 0; fm < 4; ++fm) {
          af[fm][0] = *(const short8*)&Ab[arow0 + fm * 16 * BK + ce0];
          af[fm][1] = *(const short8*)&Ab[arow0 + fm * 16 * BK + ce1];
        }
      }
      const u16* Bb = &Bs[h & 3][0];
      const short8 bf00 = *(const short8*)&Bb[brow0 + ce0];
      const short8 bf01 = *(const short8*)&Bb[brow0 + ce1];
      const short8 bf10 = *(const short8*)&Bb[brow0 + 16 * BK + ce0];
      const short8 bf11 = *(const short8*)&Bb[brow0 + 16 * BK + ce1];

      // prefetch issues (B first, then A at h==5: in-order vmcnt queue)
      if (h < 6 || k < KT - 1) {
        const int hp = (h + 2) & 7;
        const int kp = k + (h >= 6);
        STAGE_B(hp, kp, (h + 2) & 3);
      }
      if (h == 5 && k < KT - 1) STAGE_A(k + 1, (k + 1) & 1);

      __builtin_amdgcn_s_barrier();
      __builtin_amdgcn_s_setprio(1);
#pragma unroll
      for (int fm = 0; fm < 4; ++fm) {
        if (h == 0) {
          part[fm][0] = __builtin_amdgcn_mfma_f32_16x16x32_bf16(
              af[fm][0], bf00, zero4, 0, 0, 0);
          part[fm][1] = __builtin_amdgcn_mfma_f32_16x16x32_bf16(
              af[fm][0], bf10, zero4, 0, 0, 0);
        } else {
          part[fm][0] = __builtin_amdgcn_mfma_f32_16x16x32_bf16(
              af[fm][0], bf00, part[fm][0], 0, 0, 0);
          part[fm][1] = __builtin_amdgcn_mfma_f32_16x16x32_bf16(
              af[fm][0], bf10, part[fm][1], 0, 0, 0);
        }
        part[fm][0] = __builtin_amdgcn_mfma_f32_16x16x32_bf16(
            af[fm][1], bf01, part[fm][0], 0, 0, 0);
        part[fm][1] = __builtin_amdgcn_mfma_f32_16x16x32_bf16(
            af[fm][1], bf11, part[fm][1], 0, 0, 0);
      }
      __builtin_amdgcn_s_setprio(0);

      // Abel fold: acc += dg_h * P_h (dg reads are broadcast-class: only 4
      // distinct 16B addrs per wave)
#pragma unroll
      for (int fm = 0; fm < 4; ++fm) {
        const f32x4 dg =
            *(const f32x4*)&gs[h][wm * 64 + fm * 16 + (lane >> 4) * 4];
#pragma unroll
        for (int j = 0; j < 4; ++j) {
          acc[fm][0][j] += dg[j] * part[fm][0][j];
          acc[fm][1][j] += dg[j] * part[fm][1][j];
        }
      }

      // counted vmcnt per ledger
      if (h < 5) {
        asm volatile("s_waitcnt vmcnt(2)" ::: "memory");
      } else if (h == 5) {
        if (k < KT - 1) asm volatile("s_waitcnt vmcnt(4)" ::: "memory");
        else            asm volatile("s_waitcnt vmcnt(2)" ::: "memory");
      } else if (h == 6) {
        if (k < KT - 1) asm volatile("s_waitcnt vmcnt(4)" ::: "memory");
        else            asm volatile("s_waitcnt vmcnt(0)" ::: "memory");
      } else {
        if (k < KT - 1) asm volatile("s_waitcnt vmcnt(2)" ::: "memory");
        else            asm volatile("s_waitcnt vmcnt(0)" ::: "memory");
      }
      __builtin_amdgcn_s_barrier();
    }
  }

  // ---- epilogue: C/D layout col = lane&15, row = (lane>>4)*4 + j ----
  const int crow_l = wm * 64 + (lane >> 4) * 4;
  const int ccol_l = wn * 32 + (lane & 15);
#pragma unroll
  for (int fm = 0; fm < 4; ++fm) {
#pragma unroll
    for (int fn = 0; fn < 2; ++fn) {
#pragma unroll
      for (int j = 0; j < 4; ++j) {
        float b = 0.f;
#pragma unroll
        for (int h = 0; h < H_; ++h)
          b += gs[h][crow_l + fm * 16 + j] * ebs[h][ccol_l + fn * 16];
        out[(size_t)(row0 + crow_l + fm * 16 + j) * O_ +
            (col0 + ccol_l + fn * 16)] = acc[fm][fn][j] + b;
      }
    }
  }
}

// ---------------------------------------------------------------------------
extern "C" void kernel_launch(void* const* d_in, const int* in_sizes, int n_in,
                              void* d_out, int out_size, void* d_ws,
                              size_t ws_size, hipStream_t stream) {
  const float* x   = (const float*)d_in[0];
  const float* gw  = (const float*)d_in[1];
  const float* gb  = (const float*)d_in[2];
  const float* ew  = (const float*)d_in[3];
  const float* ebp = (const float*)d_in[4];
  float* out = (float*)d_out;

  u16*   x_bf = (u16*)d_ws;                                            // 16 MB
  u16*   w_bf = (u16*)((char*)d_ws + (size_t)BS_ * D_ * 2);            // 16 MB
  float* gbuf = (float*)((char*)d_ws + (size_t)BS_ * D_ * 2 +
                         (size_t)H_ * O_ * D_ * 2);                    // 256 KB

  gate_conv_kernel<<<BS_ / 4, 256, 0, stream>>>(x, gw, gb, x_bf, gbuf);
  convw_kernel<<<(H_ * O_ * D_) / 2048, 256, 0, stream>>>(ew, w_bf);
  moe_gemm_kernel<<<(BS_ / BM) * (O_ / BN), 512, 0, stream>>>(x_bf, w_bf, gbuf,
                                                              ebp, out);
}

// Round 8
// 411.109 us; speedup vs baseline: 6.7058x; 1.2741x over previous
//
#include <hip/hip_runtime.h>
#include <hip/hip_bf16.h>
#include <stdint.h>

#define B_  4
#define S_  2048
#define BS_ (B_ * S_)   // 8192 tokens
#define D_  1024
#define O_  1024
#define H_  8

#define BM 128
#define BN 128
#define BK 64
#define KT 16           // D_/BK

typedef unsigned short u16;
typedef __attribute__((ext_vector_type(8))) short     short8;
typedef __attribute__((ext_vector_type(8))) unsigned short ushort8v;
typedef __attribute__((ext_vector_type(4))) float     f32x4;

__device__ __forceinline__ u16 f2bf(float f) {
  unsigned u = __float_as_uint(f);
  unsigned r = (u + 0x7fffu + ((u >> 16) & 1u)) >> 16;
  return (u16)r;
}

#define GLOAD16(gp, lp)                                                        \
  __builtin_amdgcn_global_load_lds(                                            \
      (const __attribute__((address_space(1))) void*)(gp),                     \
      (__attribute__((address_space(3))) void*)(lp), 16, 0, 0)

// ---------------------------------------------------------------------------
// Kernel 1: gates (f32, one wave per token) + x -> bf16 conversion
// ---------------------------------------------------------------------------
__global__ __launch_bounds__(256) void gate_conv_kernel(
    const float* __restrict__ x, const float* __restrict__ gate_w,
    const float* __restrict__ gate_b, u16* __restrict__ x_bf,
    float* __restrict__ g_out) {
  const int wave  = threadIdx.x >> 6;
  const int lane  = threadIdx.x & 63;
  const int token = blockIdx.x * 4 + wave;
  const float* xr = x + (size_t)token * D_;
  const int d0 = lane * 16;

  float4 xv[4];
#pragma unroll
  for (int i = 0; i < 4; ++i) xv[i] = *(const float4*)(xr + d0 + i * 4);

  ushort8v lo, hi;
#pragma unroll
  for (int i = 0; i < 2; ++i) {
    lo[i * 4 + 0] = f2bf(xv[i].x); lo[i * 4 + 1] = f2bf(xv[i].y);
    lo[i * 4 + 2] = f2bf(xv[i].z); lo[i * 4 + 3] = f2bf(xv[i].w);
    hi[i * 4 + 0] = f2bf(xv[2 + i].x); hi[i * 4 + 1] = f2bf(xv[2 + i].y);
    hi[i * 4 + 2] = f2bf(xv[2 + i].z); hi[i * 4 + 3] = f2bf(xv[2 + i].w);
  }
  *(ushort8v*)(x_bf + (size_t)token * D_ + d0) = lo;
  *(ushort8v*)(x_bf + (size_t)token * D_ + d0 + 8) = hi;

  float s[H_];
#pragma unroll
  for (int h = 0; h < H_; ++h) {
    const float* gw = gate_w + h * D_ + d0;
    float a = 0.f;
#pragma unroll
    for (int i = 0; i < 4; ++i) {
      float4 w = *(const float4*)(gw + i * 4);
      a += xv[i].x * w.x + xv[i].y * w.y + xv[i].z * w.z + xv[i].w * w.w;
    }
    s[h] = a;
  }
#pragma unroll
  for (int h = 0; h < H_; ++h) {
#pragma unroll
    for (int off = 32; off > 0; off >>= 1) s[h] += __shfl_xor(s[h], off);
    s[h] += gate_b[h];
  }
  float m = s[0];
#pragma unroll
  for (int h = 1; h < H_; ++h) m = fmaxf(m, s[h]);
  float sum = 0.f;
#pragma unroll
  for (int h = 0; h < H_; ++h) { s[h] = expf(s[h] - m); sum += s[h]; }
  const float inv = 1.0f / sum;
#pragma unroll
  for (int h = 0; h < H_; ++h) s[h] *= inv;

  if (lane == 0) {
    float4 g0 = make_float4(s[0], s[1], s[2], s[3]);
    float4 g1 = make_float4(s[4], s[5], s[6], s[7]);
    *(float4*)(g_out + (size_t)token * H_)     = g0;
    *(float4*)(g_out + (size_t)token * H_ + 4) = g1;
  }
}

// ---------------------------------------------------------------------------
// Kernel 2: expert_w f32 -> bf16
// ---------------------------------------------------------------------------
__global__ __launch_bounds__(256) void convw_kernel(
    const float* __restrict__ w, u16* __restrict__ wb) {
  size_t i = ((size_t)blockIdx.x * 256 + threadIdx.x) * 8;
  float4 a = *(const float4*)(w + i);
  float4 b = *(const float4*)(w + i + 4);
  ushort8v v;
  v[0] = f2bf(a.x); v[1] = f2bf(a.y); v[2] = f2bf(a.z); v[3] = f2bf(a.w);
  v[4] = f2bf(b.x); v[5] = f2bf(b.y); v[6] = f2bf(b.z); v[7] = f2bf(b.w);
  *(ushort8v*)(wb + i) = v;
}

// ---------------------------------------------------------------------------
// Kernel 3: fused MoE GEMM, k-outer / h-inner, per-step transient fold.
//   out[r,c] = sum_h g[r,h]*(X[r,:]·W[h,c,:] + eb[h,c])
//            = sum_k sum_h g[r,h]*(A_k·B_{h,k})[r,c]  + bias  (fold is linear)
// BM=128 x BN=128, BK=64, 8 waves (2Mx4N, per-wave 64x32), grid=512.
// REGISTER DISCIPLINE (R4-R7 lesson: 512-thr kernels are capped at 128 VGPR
// on this toolchain; R7 still spilled ~7 dwords/step with a cross-h `part`
// prefix accumulator). This version has NO cross-step partial: each (k,h)
// step computes its K=64 slice P via a 2-MFMA chain from C=0 and folds
// immediately (acc += g_h * P). Live-across-barrier: acc(32)+af(32)+addr.
// A double-buffered (2 issues/k-tile, issued at h==5), B 4-slot ring
// (2 issues/step) prefetched 2 steps ahead, counted vmcnt (never 0
// mid-loop), 3-bit XOR swizzle (0 conflicts measured R4-R7).
// vmcnt ledger (A=2, B=2 per issue; invariant entering step s: B(s+1)=2):
//   prologue A0,B0,B1 -> vmcnt(2).
//   step (k,h): issue B(s+2) [if k<15||h<6]; issue A(k+1) at h==5 [k<15].
//   waits: h<5: 2 | h5: k<15?4:2 | h6: k<15?4:0 | h7: k<15?2:0.
// col0 = (bx&7)*BN: XCD-affine -> each XCD's 2MB W panel stays L2-resident;
// X (16 MB) serves from L3.
// ---------------------------------------------------------------------------
__global__ __launch_bounds__(512) void moe_gemm_kernel(
    const u16* __restrict__ Xb, const u16* __restrict__ Wb,
    const float* __restrict__ g, const float* __restrict__ eb,
    float* __restrict__ out) {
  __shared__ __align__(16) u16 As[2][BM * BK];   // 2 x 16 KB
  __shared__ __align__(16) u16 Bs[4][BN * BK];   // 4 x 16 KB
  __shared__ float gs[H_][BM];                   // plain gates, 4 KB
  __shared__ float ebs[H_][BN];                  // plain expert bias, 4 KB

  const int tid  = threadIdx.x;
  const int wave = tid >> 6;
  const int lane = tid & 63;

  const int bx   = blockIdx.x;          // 512 blocks; bx&7 -> XCD (W affinity)
  const int row0 = (bx >> 3) * BM;      // 64 row tiles
  const int col0 = (bx & 7) * BN;       // 8 col tiles

  // ---- stage g (transposed) and eb ----
  if (tid < BM) {
    const float* gr = g + (size_t)(row0 + tid) * H_;
#pragma unroll
    for (int h = 0; h < H_; ++h) gs[h][tid] = gr[h];
  }
  for (int i = tid; i < H_ * BN; i += 512) {
    int h = i >> 7, c = i & 127;
    ebs[h][c] = eb[h * O_ + col0 + c];
  }
  __syncthreads();

  // ---- staging geometry: linear LDS dest, inverse-swizzled global src ----
  // swizzle involution: elem_col ^= (row&7)<<3
  const int s_row = wave * 8 + (lane >> 3);
  const int s_col = ((lane & 7) * 8) ^ (((lane >> 3) & 7) << 3);
  const u16* a_base = Xb + (size_t)(row0 + s_row) * D_ + s_col;
  const int b_row   = col0 + s_row;
  const int lds_off = (wave * 8) * BK;   // elems, wave-uniform

#define STAGE_A(kk_, buf_)                                                     \
  {                                                                            \
    const u16* ap = a_base + (kk_) * BK;                                       \
    GLOAD16(ap,                    &As[buf_][lds_off]);                        \
    GLOAD16(ap + (size_t)64 * D_,  &As[buf_][lds_off + 64 * BK]);              \
  }
#define STAGE_B(hh_, kk_, sl_)                                                 \
  {                                                                            \
    const u16* bp = Wb + ((size_t)(hh_)*O_ + b_row) * D_ + (kk_)*BK + s_col;   \
    GLOAD16(bp,                    &Bs[sl_][lds_off]);                         \
    GLOAD16(bp + (size_t)64 * D_,  &Bs[sl_][lds_off + 64 * BK]);               \
  }

  // ---- swizzled LDS read offsets (elements) ----
  const int wm = wave >> 2;  // 0..1 : 64 rows
  const int wn = wave & 3;   // 0..3 : 32 cols
  const int sw  = (lane & 7) << 3;
  const int aq  = lane >> 4;
  const int ce0 = (aq * 8) ^ sw;
  const int ce1 = (aq * 8 + 32) ^ sw;
  const int arow0 = (wm * 64 + (lane & 15)) * BK;
  const int brow0 = (wn * 32 + (lane & 15)) * BK;

  const f32x4 zero4 = {0.f, 0.f, 0.f, 0.f};
  f32x4 acc[4][2];
#pragma unroll
  for (int i = 0; i < 4; ++i) { acc[i][0] = zero4; acc[i][1] = zero4; }
  short8 af[4][2];

  // ---- prologue: A0(2), B0(2), B1(2) -> wait A0,B0 ----
  STAGE_A(0, 0);
  STAGE_B(0, 0, 0);
  STAGE_B(1, 0, 1);
  asm volatile("s_waitcnt vmcnt(2)" ::: "memory");
  __builtin_amdgcn_s_barrier();

  for (int k = 0; k < KT; ++k) {
    const u16* Ab = &As[k & 1][0];
#pragma unroll
    for (int h = 0; h < H_; ++h) {
      if (h == 0) {
#pragma unroll
        for (int fm = 0; fm < 4; ++fm) {
          af[fm][0] = *(const short8*)&Ab[arow0 + fm * 16 * BK + ce0];
          af[fm][1] = *(const short8*)&Ab[arow0 + fm * 16 * BK + ce1];
        }
      }
      const u16* Bb = &Bs[h & 3][0];
      const short8 bf00 = *(const short8*)&Bb[brow0 + ce0];
      const short8 bf01 = *(const short8*)&Bb[brow0 + ce1];
      const short8 bf10 = *(const short8*)&Bb[brow0 + 16 * BK + ce0];
      const short8 bf11 = *(const short8*)&Bb[brow0 + 16 * BK + ce1];

      // prefetch issues (B first, then A at h==5: in-order vmcnt queue)
      if (h < 6 || k < KT - 1) {
        const int hp = (h + 2) & 7;
        const int kp = k + (h >= 6);
        STAGE_B(hp, kp, (h + 2) & 3);
      }
      if (h == 5 && k < KT - 1) STAGE_A(k + 1, (k + 1) & 1);

      __builtin_amdgcn_s_barrier();
      __builtin_amdgcn_s_setprio(1);
#pragma unroll
      for (int fm = 0; fm < 4; ++fm) {
        // transient K=64 slice for this (k,h): 2-MFMA chain from C=0
        f32x4 p0 = __builtin_amdgcn_mfma_f32_16x16x32_bf16(
            af[fm][0], bf00, zero4, 0, 0, 0);
        f32x4 p1 = __builtin_amdgcn_mfma_f32_16x16x32_bf16(
            af[fm][0], bf10, zero4, 0, 0, 0);
        p0 = __builtin_amdgcn_mfma_f32_16x16x32_bf16(
            af[fm][1], bf01, p0, 0, 0, 0);
        p1 = __builtin_amdgcn_mfma_f32_16x16x32_bf16(
            af[fm][1], bf11, p1, 0, 0, 0);
        // immediate fold: acc += g_h * P  (dg reads broadcast-class)
        const f32x4 gg =
            *(const f32x4*)&gs[h][wm * 64 + fm * 16 + (lane >> 4) * 4];
#pragma unroll
        for (int j = 0; j < 4; ++j) {
          acc[fm][0][j] += gg[j] * p0[j];
          acc[fm][1][j] += gg[j] * p1[j];
        }
      }
      __builtin_amdgcn_s_setprio(0);

      // counted vmcnt per ledger
      if (h < 5) {
        asm volatile("s_waitcnt vmcnt(2)" ::: "memory");
      } else if (h == 5) {
        if (k < KT - 1) asm volatile("s_waitcnt vmcnt(4)" ::: "memory");
        else            asm volatile("s_waitcnt vmcnt(2)" ::: "memory");
      } else if (h == 6) {
        if (k < KT - 1) asm volatile("s_waitcnt vmcnt(4)" ::: "memory");
        else            asm volatile("s_waitcnt vmcnt(0)" ::: "memory");
      } else {
        if (k < KT - 1) asm volatile("s_waitcnt vmcnt(2)" ::: "memory");
        else            asm volatile("s_waitcnt vmcnt(0)" ::: "memory");
      }
      __builtin_amdgcn_s_barrier();
    }
  }

  // ---- epilogue: C/D layout col = lane&15, row = (lane>>4)*4 + j ----
  const int crow_l = wm * 64 + (lane >> 4) * 4;
  const int ccol_l = wn * 32 + (lane & 15);
#pragma unroll
  for (int fm = 0; fm < 4; ++fm) {
#pragma unroll
    for (int fn = 0; fn < 2; ++fn) {
#pragma unroll
      for (int j = 0; j < 4; ++j) {
        float b = 0.f;
#pragma unroll
        for (int h = 0; h < H_; ++h)
          b += gs[h][crow_l + fm * 16 + j] * ebs[h][ccol_l + fn * 16];
        out[(size_t)(row0 + crow_l + fm * 16 + j) * O_ +
            (col0 + ccol_l + fn * 16)] = acc[fm][fn][j] + b;
      }
    }
  }
}

// ---------------------------------------------------------------------------
extern "C" void kernel_launch(void* const* d_in, const int* in_sizes, int n_in,
                              void* d_out, int out_size, void* d_ws,
                              size_t ws_size, hipStream_t stream) {
  const float* x   = (const float*)d_in[0];
  const float* gw  = (const float*)d_in[1];
  const float* gb  = (const float*)d_in[2];
  const float* ew  = (const float*)d_in[3];
  const float* ebp = (const float*)d_in[4];
  float* out = (float*)d_out;

  u16*   x_bf = (u16*)d_ws;                                            // 16 MB
  u16*   w_bf = (u16*)((char*)d_ws + (size_t)BS_ * D_ * 2);            // 16 MB
  float* gbuf = (float*)((char*)d_ws + (size_t)BS_ * D_ * 2 +
                         (size_t)H_ * O_ * D_ * 2);                    // 256 KB

  gate_conv_kernel<<<BS_ / 4, 256, 0, stream>>>(x, gw, gb, x_bf, gbuf);
  convw_kernel<<<(H_ * O_ * D_) / 2048, 256, 0, stream>>>(ew, w_bf);
  moe_gemm_kernel<<<(BS_ / BM) * (O_ / BN), 512, 0, stream>>>(x_bf, w_bf, gbuf,
                                                              ebp, out);
}